// Round 7
// baseline (588.292 us; speedup 1.0000x reference)
//
#include <hip/hip_runtime.h>
#include <stdint.h>

typedef float f32x4 __attribute__((ext_vector_type(4)));
typedef short bf16x8 __attribute__((ext_vector_type(8)));
typedef int   i32x4  __attribute__((ext_vector_type(4)));

#define IN_DIM   25088
#define OUT_DIM  4096
#define BATCH    64
#define SPLITS   28
#define KBLK     32
#define NBLK     28        // KBLK*NBLK = 896 = IN_DIM/SPLITS exactly
#define WG_N     128
#define CONV_BLOCKS 784    // 784*256*8 = 64*25088 floats

typedef const __attribute__((address_space(1))) uint32_t* gas_u32;
typedef __attribute__((address_space(3))) uint32_t* las_u32;

// fp32 -> bf16 bits, round-to-nearest-even
__device__ __forceinline__ uint32_t f2bf(float f) {
    uint32_t u = __builtin_bit_cast(uint32_t, f);
    return (u + 0x7FFFu + ((u >> 16) & 1u)) >> 16;
}

// ---- kernel 1: x fp32 -> bf16 into d_ws ----
__global__ __launch_bounds__(256) void prep(const float* __restrict__ x,
                                            uint32_t* __restrict__ xb) {
    const size_t i = blockIdx.x * 256 + threadIdx.x;  // 8 floats -> 4 u32
    const float4 v0 = *(const float4*)(x + i * 8);
    const float4 v1 = *(const float4*)(x + i * 8 + 4);
    uint4 o;
    o.x = f2bf(v0.x) | (f2bf(v0.y) << 16);
    o.y = f2bf(v0.z) | (f2bf(v0.w) << 16);
    o.z = f2bf(v1.x) | (f2bf(v1.y) << 16);
    o.w = f2bf(v1.z) | (f2bf(v1.w) << 16);
    *(uint4*)(xb + i * 4) = o;
}

// ---- kernel 2: main GEMM, async global_load_lds label pipeline ----
// Each wave stages RAW int32 labels for its own 32 rows into its own
// LDS region (wave-private double buffer -> NO barriers in the loop ->
// no vmcnt(0) drain). Counted s_waitcnt vmcnt(4) keeps the next tile's
// 4 KB/wave in flight across the MFMA phase: 16 waves/CU x 4 KB = 64 KB
// in flight per CU vs the ~9 KB Little's-law requirement for full HBM BW.
// Dequant (pair table lookup) happens at consume time, LDS->registers.
__global__ __launch_bounds__(256) void qlinear_main(
    const int*      __restrict__ labels,    // [4096, 25088] int32 in [0,32)
    const float*    __restrict__ centroids, // [32]
    const uint16_t* __restrict__ xb,        // [64, 25088] bf16 (precomputed)
    const float*    __restrict__ bias,      // [4096]
    float*          __restrict__ out)       // [64, 4096] fp32, harness-zeroed
{
    __shared__ __align__(16) uint32_t table[1024];    // 4 KB pair dequant table
    __shared__ __align__(16) uint32_t raw[2 * 4096];  // 32 KB raw label dbuf

    const int t     = threadIdx.x;
    const int wgn   = blockIdx.x & 31;      // OUT_DIM / WG_N = 32 tiles
    const int split = blockIdx.x >> 5;      // 0..27
    const int o0    = wgn * WG_N;
    const int kbase = split * (KBLK * NBLK);

    // pair table: entry i = bf16(c[i&31]) | bf16(c[i>>5])<<16 (low = earlier k)
    #pragma unroll
    for (int e = 0; e < 4; ++e) {
        const int i = t + 256 * e;
        table[i] = f2bf(centroids[i & 31]) | (f2bf(centroids[i >> 5]) << 16);
    }
    __syncthreads();   // the ONLY barrier (table visibility)

    const int lane = t & 63;
    const int wave = t >> 6;      // 0..3 -> rows [wave*32, wave*32+32)
    const int ln   = lane & 15;
    const int lq   = lane >> 4;   // 0..3 ; frag k = lq*8 + j

    // staging geometry: call c covers segs {2c, 2c+1} (seg = 16 B = 4 k).
    // lane l -> row wave*32 + (l&31), seg c*2 + (l>>5); LDS dest is
    // wave-uniform base + l*16 (hardware rule), so LDS (row,seg even s):
    //   u32 addr = buf*4096 + wave*1024 + (s>>1)*256 + (row&31)*4  (+128 for s+1)
    const int* gbase = labels + (size_t)(o0 + wave * 32 + (lane & 31)) * IN_DIM
                       + kbase + (lane >> 5) * 4;

    // x A-frag pointers: per-lane from L2-resident xb (no x LDS tile)
    const uint16_t* xp[4];
    #pragma unroll
    for (int mt = 0; mt < 4; ++mt)
        xp[mt] = xb + (size_t)(mt * 16 + ln) * IN_DIM + kbase + lq * 8;

    f32x4 acc[4][2] = {};   // [batch 16s][out 16s]

    // prologue: stage tile 0 into buf 0 (4 calls x 1 KB per wave)
    {
        uint32_t* lp = raw + wave * 1024;
        #pragma unroll
        for (int c = 0; c < 4; ++c)
            __builtin_amdgcn_global_load_lds(
                (gas_u32)(const uint32_t*)(gbase + c * 8),
                (las_u32)(lp + c * 256), 16, 0, 0);
    }

    for (int blk = 0; blk < NBLK; ++blk) {
        const int buf = blk & 1;

        // A: x A-frags for this blk (issued first: oldest in this iter's queue)
        bf16x8 a[4];
        #pragma unroll
        for (int mt = 0; mt < 4; ++mt)
            a[mt] = *(const bf16x8*)(xp[mt] + blk * KBLK);
        __builtin_amdgcn_sched_barrier(0);

        // B: stage tile blk+1 into the other buffer -> stays in flight across D
        if (blk + 1 < NBLK) {
            const int* gp = gbase + (blk + 1) * KBLK;
            uint32_t* lp = raw + (buf ^ 1) * 4096 + wave * 1024;
            #pragma unroll
            for (int c = 0; c < 4; ++c)
                __builtin_amdgcn_global_load_lds(
                    (gas_u32)(const uint32_t*)(gp + c * 8),
                    (las_u32)(lp + c * 256), 16, 0, 0);
            __builtin_amdgcn_sched_barrier(0);
            // C: wait for x frags + tile blk; keep tile blk+1's 4 calls in flight
            asm volatile("s_waitcnt vmcnt(4)" ::: "memory");
        } else {
            __builtin_amdgcn_sched_barrier(0);
            asm volatile("s_waitcnt vmcnt(0)" ::: "memory");
        }
        __builtin_amdgcn_sched_barrier(0);

        // D: dequant own rows from raw[buf] -> B-frags, MFMA
        const uint32_t* rb = raw + buf * 4096 + wave * 1024 + lq * 256;
        #pragma unroll
        for (int nt = 0; nt < 2; ++nt) {
            const uint32_t* rp = rb + (nt * 16 + ln) * 4;
            const i32x4 v0 = *(const i32x4*)rp;          // k = lq*8 .. +3
            const i32x4 v1 = *(const i32x4*)(rp + 128);  // k = lq*8+4 .. +7
            union { bf16x8 v; uint32_t u[4]; } b;
            b.u[0] = table[(uint32_t)v0.x | ((uint32_t)v0.y << 5)];
            b.u[1] = table[(uint32_t)v0.z | ((uint32_t)v0.w << 5)];
            b.u[2] = table[(uint32_t)v1.x | ((uint32_t)v1.y << 5)];
            b.u[3] = table[(uint32_t)v1.z | ((uint32_t)v1.w << 5)];
            #pragma unroll
            for (int mt = 0; mt < 4; ++mt)
                acc[mt][nt] = __builtin_amdgcn_mfma_f32_16x16x32_bf16(
                    a[mt], b.v, acc[mt][nt], 0, 0, 0);
        }
    }

    // ---- epilogue: C/D layout col=lane&15 (out), row=(lane>>4)*4+reg (batch).
    // out is harness-zeroed; split-0 blocks fold bias in exactly once per (b,o).
    #pragma unroll
    for (int mt = 0; mt < 4; ++mt)
        #pragma unroll
        for (int nt = 0; nt < 2; ++nt) {
            const int o = o0 + wave * 32 + nt * 16 + ln;
            const float badd = (split == 0) ? bias[o] : 0.0f;
            #pragma unroll
            for (int r = 0; r < 4; ++r)
                atomicAdd(out + (size_t)(mt * 16 + lq * 4 + r) * OUT_DIM + o,
                          acc[mt][nt][r] + badd);
        }
}

extern "C" void kernel_launch(void* const* d_in, const int* in_sizes, int n_in,
                              void* d_out, int out_size, void* d_ws, size_t ws_size,
                              hipStream_t stream) {
    const float* x         = (const float*)d_in[0];
    const int*   labels    = (const int*)d_in[1];
    const float* centroids = (const float*)d_in[2];
    const float* bias      = (const float*)d_in[3];
    float* out = (float*)d_out;

    uint32_t* xb = (uint32_t*)d_ws;   // 3.2 MB bf16 x

    prep<<<CONV_BLOCKS, 256, 0, stream>>>(x, xb);
    qlinear_main<<<32 * SPLITS, 256, 0, stream>>>(labels, centroids,
                                                  (const uint16_t*)xb, bias, out);
}

// Round 8
// 556.301 us; speedup vs baseline: 1.0575x; 1.0575x over previous
//
#include <hip/hip_runtime.h>
#include <stdint.h>

typedef float f32x4 __attribute__((ext_vector_type(4)));
typedef short bf16x8 __attribute__((ext_vector_type(8)));
typedef int   i32x4  __attribute__((ext_vector_type(4)));

#define IN_DIM   25088
#define OUT_DIM  4096
#define BATCH    64
#define SPLITS   14        // DIAGNOSTIC: halved grid (448 blocks), 2x work/block
#define KBLK     64
#define NBLK     28        // KBLK*NBLK = 1792 = IN_DIM/SPLITS exactly
#define WG_N     128
#define LSTR     72        // LDS row stride in bf16 elems (64 + 8 pad, 16B-aligned)

// fp32 -> bf16 bits, round-to-nearest-even
__device__ __forceinline__ uint32_t f2bf(float f) {
    uint32_t u = __builtin_bit_cast(uint32_t, f);
    return (u + 0x7FFFu + ((u >> 16) & 1u)) >> 16;
}
__device__ __forceinline__ uint32_t pack2(float a, float b) {
    return f2bf(a) | (f2bf(b) << 16);
}

// ---- single fused kernel (R6 structure verbatim; only SPLITS/NBLK changed) ----
// DIAGNOSTIC ROUND: grid halved to 448 so this dispatch exceeds the ~252 us
// poison-fill dispatches and finally appears in the top-5 WITH counters
// (FETCH_SIZE, MfmaUtil, VALUBusy, OccupancyPercent, LDS conflicts).
// Work and inner-loop structure are identical to the verified 554 us kernel.
__global__ __launch_bounds__(256) void qlinear_main(
    const int*      __restrict__ labels,    // [4096, 25088] int32 in [0,32)
    const float*    __restrict__ centroids, // [32]
    const float*    __restrict__ x,         // [64, 25088] fp32
    const float*    __restrict__ bias,      // [4096]
    float*          __restrict__ out)       // [64, 4096] fp32, harness-zeroed
{
    __shared__ __align__(16) uint32_t table[1024];       // pair dequant table
    __shared__ __align__(16) uint16_t wt[WG_N * LSTR];   // W tile [128][72] bf16
    __shared__ __align__(16) uint16_t xt[BATCH * LSTR];  // x tile [64][72] bf16

    const int t     = threadIdx.x;
    const int wgn   = blockIdx.x & 31;      // OUT_DIM / WG_N = 32 tiles
    const int split = blockIdx.x >> 5;      // 0..13
    const int o0    = wgn * WG_N;
    const int kbase = split * (KBLK * NBLK);

    // pair table: entry i = bf16(c[i&31]) | bf16(c[i>>5])<<16 (low = earlier k)
    #pragma unroll
    for (int e = 0; e < 4; ++e) {
        const int i = t + 256 * e;
        table[i] = f2bf(centroids[i & 31]) | (f2bf(centroids[i >> 5]) << 16);
    }

    const int lane = t & 63;
    const int wave = t >> 6;      // 0..3 -> 32 out-rows each
    const int ln   = lane & 15;
    const int lq   = lane >> 4;   // 0..3

    const int srow = t >> 3;        // W staging: 32 rows per pass
    const int skc  = (t & 7) * 8;   // 8 consecutive k per thread

    const int xrow = t >> 2;        // x staging: 64 rows, 4 threads/row
    const int xseg = (t & 3) * 16;  // 16 elems per thread

    // per-thread label base pointers (advance by KBLK each blk)
    const int* lbase[4];
    #pragma unroll
    for (int p = 0; p < 4; ++p)
        lbase[p] = labels + (size_t)(o0 + p * 32 + srow) * IN_DIM + kbase + skc;

    f32x4 acc[4][2] = {};   // [batch 16s][out 16s]

    // prologue: labels for blk 0 (nontemporal: 411 MB read-once stream)
    i32x4 pl[4][2];
    #pragma unroll
    for (int p = 0; p < 4; ++p) {
        pl[p][0] = __builtin_nontemporal_load((const i32x4*)lbase[p]);
        pl[p][1] = __builtin_nontemporal_load((const i32x4*)lbase[p] + 1);
    }

    for (int blk = 0; blk < NBLK; ++blk) {
        const int k0 = kbase + blk * KBLK;

        // prefetch blk+1 labels: issued a full iteration ahead of use
        i32x4 npl[4][2];
        if (blk + 1 < NBLK) {
            #pragma unroll
            for (int p = 0; p < 4; ++p) {
                const i32x4* lp = (const i32x4*)(lbase[p] + (blk + 1) * KBLK);
                npl[p][0] = __builtin_nontemporal_load(lp);
                npl[p][1] = __builtin_nontemporal_load(lp + 1);
            }
        }

        __syncthreads();   // wt/xt safe to overwrite (covers table build on blk==0)

        // ---- stage W tile from pl via pair table ----
        #pragma unroll
        for (int p = 0; p < 4; ++p) {
            const int row = p * 32 + srow;
            uint4 w;
            w.x = table[(uint32_t)pl[p][0].x | ((uint32_t)pl[p][0].y << 5)];
            w.y = table[(uint32_t)pl[p][0].z | ((uint32_t)pl[p][0].w << 5)];
            w.z = table[(uint32_t)pl[p][1].x | ((uint32_t)pl[p][1].y << 5)];
            w.w = table[(uint32_t)pl[p][1].z | ((uint32_t)pl[p][1].w << 5)];
            *(uint4*)(wt + row * LSTR + skc) = w;
        }
        // ---- stage x tile: fp32 -> bf16 in-register (x is L2/LLC-resident) ----
        {
            const float* xp = x + (size_t)xrow * IN_DIM + k0 + xseg;
            const float4 v0 = *(const float4*)xp;
            const float4 v1 = *(const float4*)(xp + 4);
            const float4 v2 = *(const float4*)(xp + 8);
            const float4 v3 = *(const float4*)(xp + 12);
            uint4 q0, q1;
            q0.x = pack2(v0.x, v0.y); q0.y = pack2(v0.z, v0.w);
            q0.z = pack2(v1.x, v1.y); q0.w = pack2(v1.z, v1.w);
            q1.x = pack2(v2.x, v2.y); q1.y = pack2(v2.z, v2.w);
            q1.z = pack2(v3.x, v3.y); q1.w = pack2(v3.z, v3.w);
            *(uint4*)(xt + xrow * LSTR + xseg)     = q0;
            *(uint4*)(xt + xrow * LSTR + xseg + 8) = q1;
        }
        __syncthreads();

        // ---- consume: 2 k-steps of 32, MFMA 16x16x32 bf16 ----
        #pragma unroll
        for (int ks = 0; ks < 2; ++ks) {
            const int kk = ks * 32 + lq * 8;   // frag: m/n = lane&15, k = (lane>>4)*8+j
            bf16x8 a[4], b[2];
            #pragma unroll
            for (int mt = 0; mt < 4; ++mt)
                a[mt] = *(const bf16x8*)(xt + (mt * 16 + ln) * LSTR + kk);
            #pragma unroll
            for (int nt = 0; nt < 2; ++nt)
                b[nt] = *(const bf16x8*)(wt + (wave * 32 + nt * 16 + ln) * LSTR + kk);
            #pragma unroll
            for (int mt = 0; mt < 4; ++mt)
                #pragma unroll
                for (int nt = 0; nt < 2; ++nt)
                    acc[mt][nt] = __builtin_amdgcn_mfma_f32_16x16x32_bf16(
                        a[mt], b[nt], acc[mt][nt], 0, 0, 0);
        }

        // rotate prefetch registers
        #pragma unroll
        for (int p = 0; p < 4; ++p) {
            pl[p][0] = npl[p][0];
            pl[p][1] = npl[p][1];
        }
    }

    // ---- epilogue: C/D layout col=lane&15 (out), row=(lane>>4)*4+reg (batch).
    // out is harness-zeroed; split-0 blocks fold bias in exactly once per (b,o).
    #pragma unroll
    for (int mt = 0; mt < 4; ++mt)
        #pragma unroll
        for (int nt = 0; nt < 2; ++nt) {
            const int o = o0 + wave * 32 + nt * 16 + ln;
            const float badd = (split == 0) ? bias[o] : 0.0f;
            #pragma unroll
            for (int r = 0; r < 4; ++r)
                atomicAdd(out + (size_t)(mt * 16 + lq * 4 + r) * OUT_DIM + o,
                          acc[mt][nt][r] + badd);
        }
}

extern "C" void kernel_launch(void* const* d_in, const int* in_sizes, int n_in,
                              void* d_out, int out_size, void* d_ws, size_t ws_size,
                              hipStream_t stream) {
    const float* x         = (const float*)d_in[0];
    const int*   labels    = (const int*)d_in[1];
    const float* centroids = (const float*)d_in[2];
    const float* bias      = (const float*)d_in[3];
    float* out = (float*)d_out;

    qlinear_main<<<32 * SPLITS, 256, 0, stream>>>(labels, centroids, x, bias, out);
}